// Round 12
// baseline (115.615 us; speedup 1.0000x reference)
//
#include <hip/hip_runtime.h>

#if __has_builtin(__builtin_amdgcn_exp2f)
#define EXP2F(x) __builtin_amdgcn_exp2f(x)
#else
#define EXP2F(x) exp2f(x)
#endif

namespace {
constexpr int B   = 2;
constexpr int CIN = 64;
constexpr int H   = 32;
constexpr int W   = 192;
constexpr int DM  = 32;
constexpr int NH  = 8;
constexpr int C   = 4;
constexpr int QS  = 24;
constexpr int FL  = 8;
constexpr int T   = 192;
constexpr int TP  = T + 2 * FL;   // 208
constexpr int M   = T / QS;       // 8
constexpr int F   = 2 * FL + QS;  // 40
constexpr int HF  = H * F;        // 1280 keys/group
constexpr int JC  = HF / 4;       // 320 keys per wave-chunk
constexpr int WP  = 196;          // padded conv row (784B pitch)
constexpr int HWP = H * WP;       // 6272

// ---- workspace layout (floats), lifetime-overlapped ----------------------
constexpr size_t XP_OFF  = 0;                          // 802,816
constexpr size_t KVI_OFF = 0;                          // 1,310,720 (XP dead)
constexpr size_t Q_OFF   = 1310720;                    // 393,216
constexpr size_t K_OFF   = Q_OFF + 393216;             // 1,703,936 ; 425,984
constexpr size_t V_OFF   = K_OFF + 425984;             // 2,129,920 ; 425,984
constexpr size_t O_OFF   = K_OFF;                      // 401,408 (K dead)
constexpr size_t ZR_OFF  = V_OFF + 425984;             // 2,555,904 ; 256 zeros
// total = 2,556,160 floats = 10.22 MB

// strides of the faithful as_strided-bug gather (uses T=192, not TP=208!)
constexpr int S0 = NH * C * H * T; // 196608
constexpr int S1 = C * H * T;      // 24576
constexpr int S2 = H * T;          // 6144
constexpr int S3 = T;              // 192

constexpr float QSC = 0.72134752044f;  // 0.5 * log2(e), folded into Q for exp2
}

// ---- prep: pad x rows to 196 + zero K/V pad cols + zero page -------------
__global__ __launch_bounds__(256) void prep_k(const float* __restrict__ x,
                                              float* __restrict__ ws) {
  int bid = blockIdx.x;
  int tid = threadIdx.x;
  if (bid < 4096) {                       // x rows: (b*64+ci)*32+y
    if (tid < WP) {
      float v = (tid >= 1 && tid <= W) ? x[(size_t)bid * W + (tid - 1)] : 0.f;
      ws[XP_OFF + (size_t)bid * WP + tid] = v;
    }
  } else if (bid < 4224) {                // K/V pad cols: 2048 rows x 16
    int t = (bid - 4096) * 256 + tid;
    int row = t >> 4;
    int p = t & 15;
    int col = (p < 8) ? p : (192 + p);
    size_t addr = (size_t)row * TP + col;
    ws[K_OFF + addr] = 0.f;
    ws[V_OFF + addr] = 0.f;
  } else {
    ws[ZR_OFF + tid] = 0.f;
  }
}

// ---- fused q/k/v conv3x3: 4 x-positions per thread -----------------------
__global__ __launch_bounds__(192) void qkv_conv_k(
    const float* __restrict__ qw, const float* __restrict__ qb,
    const float* __restrict__ kw, const float* __restrict__ kb,
    const float* __restrict__ vw, const float* __restrict__ vb,
    float* __restrict__ ws) {
  int bid = blockIdx.x;
  int yq = bid & 7;
  int co = (bid >> 3) & 31;
  int b  = bid >> 8;
  int tid = threadIdx.x;
  int yl = tid / 48;
  int xq = tid - yl * 48;
  int y  = yq * 4 + yl;
  int xp = xq * 4;

  const float* zr  = ws + ZR_OFF;
  const float* xpb = ws + XP_OFF + (size_t)b * CIN * HWP;

  const float* p0 = (y > 0)     ? xpb + (y - 1) * WP + xp : zr + xp;
  const float* p1 = xpb + y * WP + xp;
  const float* p2 = (y < H - 1) ? xpb + (y + 1) * WP + xp : zr + xp;
  int st0 = (y > 0)     ? HWP : 0;
  int st2 = (y < H - 1) ? HWP : 0;

  const float* wq = qw + co * (CIN * 9);
  const float* wk = kw + co * (CIN * 9);
  const float* wv = vw + co * (CIN * 9);

  float q0b = qb[co], k0b = kb[co], v0b = vb[co];
  float Aq[4] = {q0b, q0b, q0b, q0b};
  float Ak[4] = {k0b, k0b, k0b, k0b};
  float Av[4] = {v0b, v0b, v0b, v0b};

#pragma unroll 2
  for (int ci = 0; ci < CIN; ++ci) {
    float4 a4 = *reinterpret_cast<const float4*>(p0);
    float2 a2 = *reinterpret_cast<const float2*>(p0 + 4);
    float4 b4 = *reinterpret_cast<const float4*>(p1);
    float2 b2 = *reinterpret_cast<const float2*>(p1 + 4);
    float4 c4 = *reinterpret_cast<const float4*>(p2);
    float2 c2 = *reinterpret_cast<const float2*>(p2 + 4);
    float av_[6] = {a4.x, a4.y, a4.z, a4.w, a2.x, a2.y};
    float bv_[6] = {b4.x, b4.y, b4.z, b4.w, b2.x, b2.y};
    float cv_[6] = {c4.x, c4.y, c4.z, c4.w, c2.x, c2.y};
#pragma unroll
    for (int dx = 0; dx < 3; ++dx) {
      float wq0 = wq[dx], wq1 = wq[3 + dx], wq2 = wq[6 + dx];
      float wk0 = wk[dx], wk1 = wk[3 + dx], wk2 = wk[6 + dx];
      float wv0 = wv[dx], wv1 = wv[3 + dx], wv2 = wv[6 + dx];
#pragma unroll
      for (int o = 0; o < 4; ++o) {
        float xa = av_[o + dx], xb = bv_[o + dx], xc = cv_[o + dx];
        Aq[o] = fmaf(xa, wq0, Aq[o]); Aq[o] = fmaf(xb, wq1, Aq[o]); Aq[o] = fmaf(xc, wq2, Aq[o]);
        Ak[o] = fmaf(xa, wk0, Ak[o]); Ak[o] = fmaf(xb, wk1, Ak[o]); Ak[o] = fmaf(xc, wk2, Ak[o]);
        Av[o] = fmaf(xa, wv0, Av[o]); Av[o] = fmaf(xb, wv1, Av[o]); Av[o] = fmaf(xc, wv2, Av[o]);
      }
    }
    p0 += st0; p1 += HWP; p2 += st2;
    wq += 9; wk += 9; wv += 9;
  }

  *reinterpret_cast<float4*>(ws + Q_OFF + ((size_t)(b * DM + co) * H + y) * T + xp) =
      make_float4(Aq[0], Aq[1], Aq[2], Aq[3]);
  int h = co >> 2, c4i = co & 3;
  size_t pa = ((size_t)((b * NH + h) * C + c4i) * H + y) * TP + FL + xp;
  *reinterpret_cast<float4*>(ws + K_OFF + pa) = make_float4(Ak[0], Ak[1], Ak[2], Ak[3]);
  *reinterpret_cast<float4*>(ws + V_OFF + pa) = make_float4(Av[0], Av[1], Av[2], Av[3]);
}

// ---- build interleaved KV windows: kvi[g][j][k0..k3,v0..v3] --------------
__global__ __launch_bounds__(256) void build_kv_k(float* __restrict__ ws) {
  const float* kp = ws + K_OFF;
  const float* vp = ws + V_OFF;
  float* kvi = ws + KVI_OFF;
  int t = blockIdx.x * 256 + threadIdx.x;       // < 1,310,720
  int c  = t & 7;
  int gj = t >> 3;
  int g  = gj / HF;
  int j  = gj - g * HF;
  int b = g >> 6, h = (g >> 3) & 7, m = g & 7;
  int hh = j / F, f = j - hh * F;
  int ci = c & 3;
  const float* src = (c < 4) ? kp : vp;
  int addr = b * S0 + h * S1 + ci * S2 + hh * S3 + m * QS + f;
  kvi[t] = src[addr];
}

// ---- attention: explicit double-buffered pipeline, 2 chains, exp2 --------
// block = 4 j-chunk waves x 64 rows; grid (128 groups, 12 row-blocks)
__global__ __launch_bounds__(256) void attn_k(float* __restrict__ ws) {
  const float* qbuf = ws + Q_OFF;
  const float* kvi  = ws + KVI_OFF;
  float*       ob   = ws + O_OFF;

  int g  = blockIdx.x;                          // 0..127
  int rb = blockIdx.y;                          // 0..11
  int b = g >> 6, h = (g >> 3) & 7, m = g & 7;
  int tid = threadIdx.x;
  int row = tid & 63;
  int jc  = __builtin_amdgcn_readfirstlane(tid >> 6);

  int r  = rb * 64 + row;                       // 0..767
  int hh = r / QS, qi = r - hh * QS;
  size_t qidx = (((size_t)(b * DM + h * C) * H + hh) * T) + m * QS + qi;
  float q0 = qbuf[qidx]             * QSC;
  float q1 = qbuf[qidx + H * T]     * QSC;
  float q2 = qbuf[qidx + 2 * H * T] * QSC;
  float q3 = qbuf[qidx + 3 * H * T] * QSC;

  const float4* kvp = reinterpret_cast<const float4*>(
      kvi + ((size_t)g * HF + (size_t)jc * JC) * 8);   // 2 float4 per key

  // two independent chains (even/odd keys); explicit 1-iter-ahead prefetch
  float sA = 0.f, sB = 0.f;
  float a0 = 0.f, a1 = 0.f, a2 = 0.f, a3 = 0.f;
  float b0_ = 0.f, b1_ = 0.f, b2_ = 0.f, b3_ = 0.f;

  float4 kA = kvp[0], vA = kvp[1], kB = kvp[2], vB = kvp[3];
  kvp += 4;

#pragma unroll 2
  for (int j = 0; j < JC - 2; j += 2) {
    // issue next pair's loads before consuming current buffers
    float4 kA2 = kvp[0], vA2 = kvp[1], kB2 = kvp[2], vB2 = kvp[3];
    kvp += 4;

    float lA = fmaf(q0, kA.x, fmaf(q1, kA.y, fmaf(q2, kA.z, q3 * kA.w)));
    float lB = fmaf(q0, kB.x, fmaf(q1, kB.y, fmaf(q2, kB.z, q3 * kB.w)));
    float eA = EXP2F(lA);
    float eB = EXP2F(lB);
    sA += eA; sB += eB;
    a0 = fmaf(eA, vA.x, a0);  b0_ = fmaf(eB, vB.x, b0_);
    a1 = fmaf(eA, vA.y, a1);  b1_ = fmaf(eB, vB.y, b1_);
    a2 = fmaf(eA, vA.z, a2);  b2_ = fmaf(eB, vB.z, b2_);
    a3 = fmaf(eA, vA.w, a3);  b3_ = fmaf(eB, vB.w, b3_);

    kA = kA2; vA = vA2; kB = kB2; vB = vB2;
  }
  {
    // epilogue: last pair
    float lA = fmaf(q0, kA.x, fmaf(q1, kA.y, fmaf(q2, kA.z, q3 * kA.w)));
    float lB = fmaf(q0, kB.x, fmaf(q1, kB.y, fmaf(q2, kB.z, q3 * kB.w)));
    float eA = EXP2F(lA);
    float eB = EXP2F(lB);
    sA += eA; sB += eB;
    a0 = fmaf(eA, vA.x, a0);  b0_ = fmaf(eB, vB.x, b0_);
    a1 = fmaf(eA, vA.y, a1);  b1_ = fmaf(eB, vB.y, b1_);
    a2 = fmaf(eA, vA.z, a2);  b2_ = fmaf(eB, vB.z, b2_);
    a3 = fmaf(eA, vA.w, a3);  b3_ = fmaf(eB, vB.w, b3_);
  }
  float s  = sA + sB;
  float o0 = a0 + b0_, o1 = a1 + b1_, o2 = a2 + b2_, o3 = a3 + b3_;

  __shared__ float red[4][64][5];
  red[jc][row][0] = s;
  red[jc][row][1] = o0;
  red[jc][row][2] = o1;
  red[jc][row][3] = o2;
  red[jc][row][4] = o3;
  __syncthreads();

  if (tid < 64) {                               // row == tid here
    float S = 0.f, O0 = 0.f, O1 = 0.f, O2 = 0.f, O3 = 0.f;
#pragma unroll
    for (int cx = 0; cx < 4; ++cx) {
      S  += red[cx][tid][0];
      O0 += red[cx][tid][1];
      O1 += red[cx][tid][2];
      O2 += red[cx][tid][3];
      O3 += red[cx][tid][4];
    }
    float inv = 1.0f / S;
    // padded O: row stride WP=196, interior offset +1
    size_t obase = (((size_t)(b * DM + h * C) * H + hh) * WP) + 1 + m * QS + qi;
    ob[obase]            = O0 * inv;
    ob[obase + HWP]      = O1 * inv;
    ob[obase + 2 * HWP]  = O2 * inv;
    ob[obase + 3 * HWP]  = O3 * inv;
    if (m == 0 && qi == 0) {                    // zero pad col 0
      ob[obase - 1] = 0.f; ob[obase - 1 + HWP] = 0.f;
      ob[obase - 1 + 2 * HWP] = 0.f; ob[obase - 1 + 3 * HWP] = 0.f;
    }
    if (m == M - 1 && qi == QS - 1) {           // zero pad col 193
      ob[obase + 1] = 0.f; ob[obase + 1 + HWP] = 0.f;
      ob[obase + 1 + 2 * HWP] = 0.f; ob[obase + 1 + 3 * HWP] = 0.f;
    }
  }
}

// ---- output conv3x3 (32 -> 64): 2 co x 4 x per thread --------------------
__global__ __launch_bounds__(192) void out_conv_k(const float* __restrict__ ws,
                                                  const float* __restrict__ ow,
                                                  float* __restrict__ out) {
  int bid = blockIdx.x;
  int yq = bid & 7;
  int cp = (bid >> 3) & 31;
  int b  = bid >> 8;
  int tid = threadIdx.x;
  int yl = tid / 48;
  int xq = tid - yl * 48;
  int y  = yq * 4 + yl;
  int xp = xq * 4;

  const float* zr  = ws + ZR_OFF;
  const float* obb = ws + O_OFF + (size_t)b * DM * HWP;

  const float* p0 = (y > 0)     ? obb + (y - 1) * WP + xp : zr + xp;
  const float* p1 = obb + y * WP + xp;
  const float* p2 = (y < H - 1) ? obb + (y + 1) * WP + xp : zr + xp;
  int st0 = (y > 0)     ? HWP : 0;
  int st2 = (y < H - 1) ? HWP : 0;

  int co0 = cp * 2;
  const float* w0 = ow + (size_t)co0 * (DM * 9);
  const float* w1 = w0 + DM * 9;
  float A0[4] = {0.f, 0.f, 0.f, 0.f};
  float A1[4] = {0.f, 0.f, 0.f, 0.f};

#pragma unroll 2
  for (int ci = 0; ci < DM; ++ci) {
    float4 a4 = *reinterpret_cast<const float4*>(p0);
    float2 a2 = *reinterpret_cast<const float2*>(p0 + 4);
    float4 b4 = *reinterpret_cast<const float4*>(p1);
    float2 b2 = *reinterpret_cast<const float2*>(p1 + 4);
    float4 c4 = *reinterpret_cast<const float4*>(p2);
    float2 c2 = *reinterpret_cast<const float2*>(p2 + 4);
    float av_[6] = {a4.x, a4.y, a4.z, a4.w, a2.x, a2.y};
    float bv_[6] = {b4.x, b4.y, b4.z, b4.w, b2.x, b2.y};
    float cv_[6] = {c4.x, c4.y, c4.z, c4.w, c2.x, c2.y};
#pragma unroll
    for (int dx = 0; dx < 3; ++dx) {
      float u0 = w0[dx], u1 = w0[3 + dx], u2 = w0[6 + dx];
      float t0 = w1[dx], t1 = w1[3 + dx], t2 = w1[6 + dx];
#pragma unroll
      for (int o = 0; o < 4; ++o) {
        float xa = av_[o + dx], xb = bv_[o + dx], xc = cv_[o + dx];
        A0[o] = fmaf(xa, u0, A0[o]); A0[o] = fmaf(xb, u1, A0[o]); A0[o] = fmaf(xc, u2, A0[o]);
        A1[o] = fmaf(xa, t0, A1[o]); A1[o] = fmaf(xb, t1, A1[o]); A1[o] = fmaf(xc, t2, A1[o]);
      }
    }
    p0 += st0; p1 += HWP; p2 += st2;
    w0 += 9; w1 += 9;
  }

  size_t ob0 = ((size_t)(b * 64 + co0) * H + y) * W + xp;
  *reinterpret_cast<float4*>(out + ob0)         = make_float4(A0[0], A0[1], A0[2], A0[3]);
  *reinterpret_cast<float4*>(out + ob0 + H * W) = make_float4(A1[0], A1[1], A1[2], A1[3]);
}

extern "C" void kernel_launch(void* const* d_in, const int* in_sizes, int n_in,
                              void* d_out, int out_size, void* d_ws, size_t ws_size,
                              hipStream_t stream) {
  const float* x  = (const float*)d_in[0];
  const float* qw = (const float*)d_in[1];
  const float* qb = (const float*)d_in[2];
  const float* kw = (const float*)d_in[3];
  const float* kb = (const float*)d_in[4];
  const float* vw = (const float*)d_in[5];
  const float* vb = (const float*)d_in[6];
  const float* ow = (const float*)d_in[7];
  float* out = (float*)d_out;
  float* ws  = (float*)d_ws;

  hipLaunchKernelGGL(prep_k,     dim3(4225), dim3(256), 0, stream, x, ws);
  hipLaunchKernelGGL(qkv_conv_k, dim3(512),  dim3(192), 0, stream,
                     qw, qb, kw, kb, vw, vb, ws);
  hipLaunchKernelGGL(build_kv_k, dim3(5120), dim3(256), 0, stream, ws);
  hipLaunchKernelGGL(attn_k,     dim3(128, 12), dim3(256), 0, stream, ws);
  hipLaunchKernelGGL(out_conv_k, dim3(512),  dim3(192), 0, stream, ws, ow, out);
}